// Round 5
// baseline (612.094 us; speedup 1.0000x reference)
//
#include <hip/hip_runtime.h>
#include <hip/hip_bf16.h>

// Problem: B=8, C=256, H=W=64 -> N=4096, inter=32. fp32 in/out.
#define BB 8
#define CC 256
#define NN 4096
#define II 32

typedef __bf16 bf16_t;
typedef bf16_t bf16x8 __attribute__((ext_vector_type(8)));
typedef float f32x4 __attribute__((ext_vector_type(4)));

// ---------------------------------------------------------------------------
// Weight pre-convert: Wb[320][256] bf16 = [Wq(32); Wk(32); Wv(256)] rows.
// ---------------------------------------------------------------------------
__global__ __launch_bounds__(256) void wconv(
    const float* __restrict__ Wq, const float* __restrict__ Wk,
    const float* __restrict__ Wv, bf16_t* __restrict__ Wb) {
  int idx = blockIdx.x * 256 + threadIdx.x;  // < 320*256
  int o = idx >> 8, c = idx & 255;
  float w = (o < 32) ? Wq[o * 256 + c]
          : (o < 64) ? Wk[(o - 32) * 256 + c]
                     : Wv[(o - 64) * 256 + c];
  Wb[idx] = (bf16_t)w;
}

// ---------------------------------------------------------------------------
// x transpose+convert: xt[b][n][c] bf16 from x[b][c][n] fp32.
// ---------------------------------------------------------------------------
__global__ __launch_bounds__(256) void xcvt(
    const float* __restrict__ x, bf16_t* __restrict__ xt) {
  __shared__ bf16_t tl[64][72];  // [n][c], padded
  const int t  = threadIdx.x;
  const int n0 = blockIdx.x * 64, c0 = blockIdx.y * 64, b = blockIdx.z;

  const float* xb = x + ((size_t)b * CC + c0) * NN + n0;
#pragma unroll
  for (int p = 0; p < 4; ++p) {
    int cl = (t >> 4) + 16 * p;
    int nl = (t & 15) * 4;
    float4 v = *(const float4*)&xb[(size_t)cl * NN + nl];
    tl[nl + 0][cl] = (bf16_t)v.x;
    tl[nl + 1][cl] = (bf16_t)v.y;
    tl[nl + 2][cl] = (bf16_t)v.z;
    tl[nl + 3][cl] = (bf16_t)v.w;
  }
  __syncthreads();
  bf16_t* xtb = xt + ((size_t)b * NN + n0) * CC + c0;
#pragma unroll
  for (int p = 0; p < 4; ++p) {
    int nl = (t >> 4) + 16 * p;
    int cl = (t & 15) * 4;
    union { bf16_t h[4]; uint2 u; } pk;
    pk.h[0] = tl[nl][cl + 0]; pk.h[1] = tl[nl][cl + 1];
    pk.h[2] = tl[nl][cl + 2]; pk.h[3] = tl[nl][cl + 3];
    *(uint2*)&xtb[(size_t)nl * CC + cl] = pk.u;
  }
}

// ---------------------------------------------------------------------------
// Fused q/k/v projection as MFMA GEMM (unchanged).
// ---------------------------------------------------------------------------
__global__ __launch_bounds__(256, 4) void qkv_proj(
    const bf16_t* __restrict__ xt, const bf16_t* __restrict__ Wb,
    const float* __restrict__ bq, const float* __restrict__ bk,
    const float* __restrict__ bv,
    bf16_t* __restrict__ q, bf16_t* __restrict__ k, bf16_t* __restrict__ v) {
  const int t  = threadIdx.x;
  const int w  = t >> 6;
  const int l  = t & 63;
  const int lo = l & 15;
  const int q4 = l >> 4;
  const int og = blockIdx.y;  // o-tile group: tiles [og*5, og*5+5)
  const int b  = blockIdx.z;
  const int nbase = blockIdx.x * 128 + w * 32;

  const bf16_t* xb = xt + (size_t)b * NN * CC;

  f32x4 acc[5][2];  // [o-tile][n-subtile]
#pragma unroll
  for (int ot = 0; ot < 5; ++ot)
#pragma unroll
    for (int ms = 0; ms < 2; ++ms) acc[ot][ms] = (f32x4){0.f, 0.f, 0.f, 0.f};

#pragma unroll 2
  for (int ks = 0; ks < 8; ++ks) {
    const int c0 = ks * 32 + q4 * 8;
    bf16x8 af[2];
#pragma unroll
    for (int ms = 0; ms < 2; ++ms)
      af[ms] = *(const bf16x8*)&xb[(size_t)(nbase + ms * 16 + lo) * CC + c0];
    bf16x8 bw[5];
#pragma unroll
    for (int ot = 0; ot < 5; ++ot)
      bw[ot] = *(const bf16x8*)&Wb[((og * 5 + ot) * 16 + lo) * 256 + c0];
#pragma unroll
    for (int ms = 0; ms < 2; ++ms)
#pragma unroll
      for (int ot = 0; ot < 5; ++ot)
        acc[ot][ms] = __builtin_amdgcn_mfma_f32_16x16x32_bf16(
            af[ms], bw[ot], acc[ot][ms], 0, 0, 0);
  }

  // Epilogue: q,k -> [b][n][32] bf16 (2B scatter); v -> [b][c][n] bf16.
#pragma unroll
  for (int ot = 0; ot < 5; ++ot) {
    const int gt = og * 5 + ot;  // global o-tile
    if (gt < 4) {
      const bool isq = gt < 2;
      const int i = (gt & 1) * 16 + lo;
      const float bias = isq ? bq[i] : bk[i];
      bf16_t* dst = (isq ? q : k) + (size_t)b * NN * II;
#pragma unroll
      for (int ms = 0; ms < 2; ++ms) {
#pragma unroll
        for (int r = 0; r < 4; ++r) {
          int n = nbase + ms * 16 + q4 * 4 + r;
          dst[(size_t)n * II + i] = (bf16_t)(acc[ot][ms][r] + bias);
        }
      }
    } else {
      const int cv = (gt - 4) * 16 + lo;
      const float bias = bv[cv];
      bf16_t* dst = v + ((size_t)b * CC + cv) * NN;
#pragma unroll
      for (int ms = 0; ms < 2; ++ms) {
        union { bf16_t h[4]; uint2 u; } pk;
#pragma unroll
        for (int r = 0; r < 4; ++r) pk.h[r] = (bf16_t)(acc[ot][ms][r] + bias);
        *(uint2*)&dst[nbase + ms * 16 + q4 * 4] = pk.u;
      }
    }
  }
}

// ---------------------------------------------------------------------------
// Full-C zero-shuffle MFMA attention, NAMED double-buffered prefetch.
// Wave: m-tile 16, ALL 256 channels (16 ct) -> every score exp'd ONCE
// (round 3 lesson: replication made it VALU-bound). Round-4 lesson: same-
// chunk V loads let the compiler serialize them (VGPR_Count=84, 6% mfma);
// fix = round-2/3's proven pattern: issue NEXT chunk's 18 loads into the
// OTHER named buffer, sched_barrier(0) pins them above compute, swap via
// two-phase manual unroll (no array copies, no dynamic indexing).
// Layout (harness-verified rounds 0-4):
//   QK: 2 mfma(kf_s, qf), K rows PERMUTED (lane lo, sub s holds K row
//       (lo>>2)*8 + s*4 + (lo&3)) so lane (lo,q4) reg r of sub s gets
//       S[n = q4*8+s*4+r][m = lo] = the 8 consecutive n for the PV A-frag;
//   exp -> 8 bf16 -> pf (lane-local, zero cross-lane);
//   PV: acc[ct] = mfma(pf, vf[ct], acc[ct]) -> O[m = q4*4+r][c = ct*16+lo].
// Grid: 8 b x 64 mg x 4 waves/block = 2048 waves = exactly 2/SIMD resident
// (VGPR ~235 under the 256 cap of __launch_bounds__(256,2)), zero tail.
// Block's 4 waves issue IDENTICAL V/K addresses -> L1 dedup; L2 V-traffic
// 512 x 2MB ~ 19 TB/s at target speed, under the 34.5 ceiling.
// bid&7 batch->XCD pinning: V[b] 2MB + K[b] 256KB fit per-XCD 4MB L2.
// ---------------------------------------------------------------------------
__global__ __launch_bounds__(256, 2) void attn_fc(
    const bf16_t* __restrict__ q, const bf16_t* __restrict__ k,
    const bf16_t* __restrict__ v, const float* __restrict__ x,
    const float* __restrict__ gamma, float* __restrict__ out) {
  const int t  = threadIdx.x;
  const int w  = t >> 6;
  const int l  = t & 63;
  const int lo = l & 15;
  const int q4 = l >> 4;

  const int bid = blockIdx.x;
  const int b   = bid & 7;             // XCD-aligned batch
  const int mg  = bid >> 3;            // m-group (4 m-tiles of 16)
  const int m0  = (mg * 4 + w) * 16;

  const bf16_t* qb = q + (size_t)b * NN * II;
  const bf16_t* kb = k + (size_t)b * NN * II;
  const bf16_t* vb = v + (size_t)b * CC * NN;
  const bf16_t* vbl = vb + (size_t)lo * NN + q4 * 8;  // per-lane V base

  // Q B-frag, loop-invariant
  bf16x8 qf = *(const bf16x8*)(qb + (size_t)(m0 + lo) * II + q4 * 8);

  f32x4 acc[16];  // [ct] -> O[m = m0+q4*4+r][c = ct*16+lo]
#pragma unroll
  for (int ct = 0; ct < 16; ++ct) acc[ct] = (f32x4){0.f, 0.f, 0.f, 0.f};
  float lp = 0.f;

  const f32x4 zero = (f32x4){0.f, 0.f, 0.f, 0.f};
  const int kperm = ((lo >> 2) << 3) | (lo & 3);  // + s*4 + n1

  // ---- prime chunk 0 into buffer A ----
  bf16x8 kf0A = *(const bf16x8*)(kb + (size_t)(kperm + 0) * II + q4 * 8);
  bf16x8 kf1A = *(const bf16x8*)(kb + (size_t)(kperm + 4) * II + q4 * 8);
  bf16x8 vfA[16];
#pragma unroll
  for (int ct = 0; ct < 16; ++ct)
    vfA[ct] = *(const bf16x8*)(vbl + (size_t)(ct * 16) * NN);
  bf16x8 kf0B, kf1B, vfB[16];

  for (int n1 = 0; n1 < NN; n1 += 64) {
    // ======== phase A: prefetch n1+32 -> B; compute chunk n1 from A ========
    {
      const int nn = n1 + 32;  // always < NN here
      kf0B = *(const bf16x8*)(kb + (size_t)(nn + kperm + 0) * II + q4 * 8);
      kf1B = *(const bf16x8*)(kb + (size_t)(nn + kperm + 4) * II + q4 * 8);
#pragma unroll
      for (int ct = 0; ct < 16; ++ct)
        vfB[ct] = *(const bf16x8*)(vbl + (size_t)(ct * 16) * NN + nn);
      __builtin_amdgcn_sched_barrier(0);  // pin loads above compute

      f32x4 s0 = __builtin_amdgcn_mfma_f32_16x16x32_bf16(kf0A, qf, zero, 0, 0, 0);
      f32x4 s1 = __builtin_amdgcn_mfma_f32_16x16x32_bf16(kf1A, qf, zero, 0, 0, 0);
      float e0 = __expf(s0[0]), e1 = __expf(s0[1]), e2 = __expf(s0[2]), e3 = __expf(s0[3]);
      float e4 = __expf(s1[0]), e5 = __expf(s1[1]), e6 = __expf(s1[2]), e7 = __expf(s1[3]);
      lp += (((e0 + e1) + (e2 + e3)) + ((e4 + e5) + (e6 + e7)));
      union { bf16_t h[8]; bf16x8 v8; } pk_;
      pk_.h[0] = (bf16_t)e0; pk_.h[1] = (bf16_t)e1;
      pk_.h[2] = (bf16_t)e2; pk_.h[3] = (bf16_t)e3;
      pk_.h[4] = (bf16_t)e4; pk_.h[5] = (bf16_t)e5;
      pk_.h[6] = (bf16_t)e6; pk_.h[7] = (bf16_t)e7;
      bf16x8 pf = pk_.v8;

      __builtin_amdgcn_s_setprio(1);
#pragma unroll
      for (int ct = 0; ct < 16; ++ct)
        acc[ct] = __builtin_amdgcn_mfma_f32_16x16x32_bf16(pf, vfA[ct], acc[ct], 0, 0, 0);
      __builtin_amdgcn_s_setprio(0);
    }
    // ======== phase B: prefetch n1+64 -> A; compute chunk n1+32 from B =====
    {
      const int nn = (n1 + 64) & (NN - 1);  // wraps to 0 on last iter (discarded)
      kf0A = *(const bf16x8*)(kb + (size_t)(nn + kperm + 0) * II + q4 * 8);
      kf1A = *(const bf16x8*)(kb + (size_t)(nn + kperm + 4) * II + q4 * 8);
#pragma unroll
      for (int ct = 0; ct < 16; ++ct)
        vfA[ct] = *(const bf16x8*)(vbl + (size_t)(ct * 16) * NN + nn);
      __builtin_amdgcn_sched_barrier(0);  // pin loads above compute

      f32x4 s0 = __builtin_amdgcn_mfma_f32_16x16x32_bf16(kf0B, qf, zero, 0, 0, 0);
      f32x4 s1 = __builtin_amdgcn_mfma_f32_16x16x32_bf16(kf1B, qf, zero, 0, 0, 0);
      float e0 = __expf(s0[0]), e1 = __expf(s0[1]), e2 = __expf(s0[2]), e3 = __expf(s0[3]);
      float e4 = __expf(s1[0]), e5 = __expf(s1[1]), e6 = __expf(s1[2]), e7 = __expf(s1[3]);
      lp += (((e0 + e1) + (e2 + e3)) + ((e4 + e5) + (e6 + e7)));
      union { bf16_t h[8]; bf16x8 v8; } pk_;
      pk_.h[0] = (bf16_t)e0; pk_.h[1] = (bf16_t)e1;
      pk_.h[2] = (bf16_t)e2; pk_.h[3] = (bf16_t)e3;
      pk_.h[4] = (bf16_t)e4; pk_.h[5] = (bf16_t)e5;
      pk_.h[6] = (bf16_t)e6; pk_.h[7] = (bf16_t)e7;
      bf16x8 pf = pk_.v8;

      __builtin_amdgcn_s_setprio(1);
#pragma unroll
      for (int ct = 0; ct < 16; ++ct)
        acc[ct] = __builtin_amdgcn_mfma_f32_16x16x32_bf16(pf, vfB[ct], acc[ct], 0, 0, 0);
      __builtin_amdgcn_s_setprio(0);
    }
  }

  // ---- denom reduce (wave-local): lanes {lo,+16,+32,+48} -> sum for m0+lo ----
  float s = lp;
  s += __shfl_xor(s, 16);
  s += __shfl_xor(s, 32);
  f32x4 linv;
#pragma unroll
  for (int r = 0; r < 4; ++r) linv[r] = 1.0f / __shfl(s, q4 * 4 + r);

  // ---- epilogue: out = gamma * O/l + x (contiguous float4 per lane) ----
  const float g = gamma[0];
#pragma unroll
  for (int ct = 0; ct < 16; ++ct) {
    const size_t row = ((size_t)b * CC + ct * 16 + lo) * NN + m0 + q4 * 4;
    float4 xv = *(const float4*)(x + row);
    float4 ov;
    ov.x = g * acc[ct][0] * linv[0] + xv.x;
    ov.y = g * acc[ct][1] * linv[1] + xv.y;
    ov.z = g * acc[ct][2] * linv[2] + xv.z;
    ov.w = g * acc[ct][3] * linv[3] + xv.w;
    *(float4*)(out + row) = ov;
  }
}

// ---------------------------------------------------------------------------
extern "C" void kernel_launch(void* const* d_in, const int* in_sizes, int n_in,
                              void* d_out, int out_size, void* d_ws, size_t ws_size,
                              hipStream_t stream) {
  const float* x     = (const float*)d_in[0];
  const float* Wq    = (const float*)d_in[1];
  const float* bq    = (const float*)d_in[2];
  const float* Wk    = (const float*)d_in[3];
  const float* bk    = (const float*)d_in[4];
  const float* Wv    = (const float*)d_in[5];
  const float* bv    = (const float*)d_in[6];
  const float* gamma = (const float*)d_in[7];
  float* out = (float*)d_out;

  // Workspace (bf16): q 2MB, k 2MB, v 16MB, Wb 160KB, xt 16MB (~36.2MB)
  bf16_t* ws = (bf16_t*)d_ws;
  bf16_t* q  = ws;
  bf16_t* k  = q + (size_t)BB * NN * II;
  bf16_t* v  = k + (size_t)BB * NN * II;
  bf16_t* Wb = v + (size_t)BB * CC * NN;
  bf16_t* xt = Wb + (size_t)320 * 256;

  wconv<<<dim3(320), 256, 0, stream>>>(Wq, Wk, Wv, Wb);

  dim3 gx(NN / 64, CC / 64, BB);
  xcvt<<<gx, 256, 0, stream>>>(x, xt);

  dim3 gp(NN / 128, 4, BB);
  qkv_proj<<<gp, 256, 0, stream>>>(xt, Wb, bq, bk, bv, q, k, v);

  attn_fc<<<dim3(512), 256, 0, stream>>>(q, k, v, x, gamma, out);
}

// Round 6
// 255.393 us; speedup vs baseline: 2.3967x; 2.3967x over previous
//
#include <hip/hip_runtime.h>
#include <hip/hip_bf16.h>

// Problem: B=8, C=256, H=W=64 -> N=4096, inter=32. fp32 in/out.
#define BB 8
#define CC 256
#define NN 4096
#define II 32

typedef __bf16 bf16_t;
typedef bf16_t bf16x8 __attribute__((ext_vector_type(8)));
typedef float f32x4 __attribute__((ext_vector_type(4)));

// ---------------------------------------------------------------------------
// Weight pre-convert: Wb[320][256] bf16 = [Wq(32); Wk(32); Wv(256)] rows.
// ---------------------------------------------------------------------------
__global__ __launch_bounds__(256) void wconv(
    const float* __restrict__ Wq, const float* __restrict__ Wk,
    const float* __restrict__ Wv, bf16_t* __restrict__ Wb) {
  int idx = blockIdx.x * 256 + threadIdx.x;  // < 320*256
  int o = idx >> 8, c = idx & 255;
  float w = (o < 32) ? Wq[o * 256 + c]
          : (o < 64) ? Wk[(o - 32) * 256 + c]
                     : Wv[(o - 64) * 256 + c];
  Wb[idx] = (bf16_t)w;
}

// ---------------------------------------------------------------------------
// x transpose+convert: xt[b][n][c] bf16 from x[b][c][n] fp32.
// ---------------------------------------------------------------------------
__global__ __launch_bounds__(256) void xcvt(
    const float* __restrict__ x, bf16_t* __restrict__ xt) {
  __shared__ bf16_t tl[64][72];  // [n][c], padded
  const int t  = threadIdx.x;
  const int n0 = blockIdx.x * 64, c0 = blockIdx.y * 64, b = blockIdx.z;

  const float* xb = x + ((size_t)b * CC + c0) * NN + n0;
#pragma unroll
  for (int p = 0; p < 4; ++p) {
    int cl = (t >> 4) + 16 * p;
    int nl = (t & 15) * 4;
    float4 v = *(const float4*)&xb[(size_t)cl * NN + nl];
    tl[nl + 0][cl] = (bf16_t)v.x;
    tl[nl + 1][cl] = (bf16_t)v.y;
    tl[nl + 2][cl] = (bf16_t)v.z;
    tl[nl + 3][cl] = (bf16_t)v.w;
  }
  __syncthreads();
  bf16_t* xtb = xt + ((size_t)b * NN + n0) * CC + c0;
#pragma unroll
  for (int p = 0; p < 4; ++p) {
    int nl = (t >> 4) + 16 * p;
    int cl = (t & 15) * 4;
    union { bf16_t h[4]; uint2 u; } pk;
    pk.h[0] = tl[nl][cl + 0]; pk.h[1] = tl[nl][cl + 1];
    pk.h[2] = tl[nl][cl + 2]; pk.h[3] = tl[nl][cl + 3];
    *(uint2*)&xtb[(size_t)nl * CC + cl] = pk.u;
  }
}

// ---------------------------------------------------------------------------
// Fused q/k/v projection as MFMA GEMM (unchanged).
// ---------------------------------------------------------------------------
__global__ __launch_bounds__(256, 4) void qkv_proj(
    const bf16_t* __restrict__ xt, const bf16_t* __restrict__ Wb,
    const float* __restrict__ bq, const float* __restrict__ bk,
    const float* __restrict__ bv,
    bf16_t* __restrict__ q, bf16_t* __restrict__ k, bf16_t* __restrict__ v) {
  const int t  = threadIdx.x;
  const int w  = t >> 6;
  const int l  = t & 63;
  const int lo = l & 15;
  const int q4 = l >> 4;
  const int og = blockIdx.y;  // o-tile group: tiles [og*5, og*5+5)
  const int b  = blockIdx.z;
  const int nbase = blockIdx.x * 128 + w * 32;

  const bf16_t* xb = xt + (size_t)b * NN * CC;

  f32x4 acc[5][2];  // [o-tile][n-subtile]
#pragma unroll
  for (int ot = 0; ot < 5; ++ot)
#pragma unroll
    for (int ms = 0; ms < 2; ++ms) acc[ot][ms] = (f32x4){0.f, 0.f, 0.f, 0.f};

#pragma unroll 2
  for (int ks = 0; ks < 8; ++ks) {
    const int c0 = ks * 32 + q4 * 8;
    bf16x8 af[2];
#pragma unroll
    for (int ms = 0; ms < 2; ++ms)
      af[ms] = *(const bf16x8*)&xb[(size_t)(nbase + ms * 16 + lo) * CC + c0];
    bf16x8 bw[5];
#pragma unroll
    for (int ot = 0; ot < 5; ++ot)
      bw[ot] = *(const bf16x8*)&Wb[((og * 5 + ot) * 16 + lo) * 256 + c0];
#pragma unroll
    for (int ms = 0; ms < 2; ++ms)
#pragma unroll
      for (int ot = 0; ot < 5; ++ot)
        acc[ot][ms] = __builtin_amdgcn_mfma_f32_16x16x32_bf16(
            af[ms], bw[ot], acc[ot][ms], 0, 0, 0);
  }

  // Epilogue: q,k -> [b][n][32] bf16 (2B scatter); v -> [b][c][n] bf16.
#pragma unroll
  for (int ot = 0; ot < 5; ++ot) {
    const int gt = og * 5 + ot;  // global o-tile
    if (gt < 4) {
      const bool isq = gt < 2;
      const int i = (gt & 1) * 16 + lo;
      const float bias = isq ? bq[i] : bk[i];
      bf16_t* dst = (isq ? q : k) + (size_t)b * NN * II;
#pragma unroll
      for (int ms = 0; ms < 2; ++ms) {
#pragma unroll
        for (int r = 0; r < 4; ++r) {
          int n = nbase + ms * 16 + q4 * 4 + r;
          dst[(size_t)n * II + i] = (bf16_t)(acc[ot][ms][r] + bias);
        }
      }
    } else {
      const int cv = (gt - 4) * 16 + lo;
      const float bias = bv[cv];
      bf16_t* dst = v + ((size_t)b * CC + cv) * NN;
#pragma unroll
      for (int ms = 0; ms < 2; ++ms) {
        union { bf16_t h[4]; uint2 u; } pk;
#pragma unroll
        for (int r = 0; r < 4; ++r) pk.h[r] = (bf16_t)(acc[ot][ms][r] + bias);
        *(uint2*)&dst[nbase + ms * 16 + q4 * 4] = pk.u;
      }
    }
  }
}

// ---------------------------------------------------------------------------
// MFMA attention (round-0 verified structure) + RELAXED BARRIER (T4).
// Block: batch b, 64 queries [m0,m0+64). 4 waves; wave w owns c-range
// [w*64, w*64+64). N-loop in tiles of 64.
//   Top of iter: issue ALL 8 V-frag b128 loads + next iter's K-frag load.
//   Phase 1: S_T[n-sub w][all m] = K.Q^T (4 mfma), exp -> bf16 P to LDS
//            (double-buffered, XOR-swizzled chunks).
//   RELAXED barrier: s_waitcnt lgkmcnt(0) (drain own ds_writes) + raw
//   s_barrier + sched_barrier(0). Unlike __syncthreads (which emits
//   vmcnt(0) and drained the V/K prefetch EVERY iter = the round-0 stall),
//   this leaves the 9 global loads in flight across the barrier; the
//   compiler inserts counted vmcnt at the PV uses. Double-buffered P keeps
//   the one-barrier/iter scheme race-free (ahead-runner writes the OTHER
//   buffer; can't pass barrier i+1 until all waves left phase-2 of i).
//   Phase 2: O[c][m] += V.P^T (32 mfma, setprio-wrapped), P B-frags b128
//   from LDS.
// No max-subtraction: |s|<~35, exp fits fp32/bf16 range; partials add.
// ---------------------------------------------------------------------------
__global__ __launch_bounds__(256, 2) void attn_mfma(
    const bf16_t* __restrict__ q, const bf16_t* __restrict__ k,
    const bf16_t* __restrict__ v, const float* __restrict__ x,
    const float* __restrict__ gamma, float* __restrict__ out) {
  __shared__ bf16_t Pld[2][64 * 64];  // 16 KB double-buffered P
  __shared__ float lred[16][64];
  __shared__ float lfin[64];

  const int t  = threadIdx.x;
  const int w  = t >> 6;   // wave id = c-split
  const int l  = t & 63;
  const int lo = l & 15;
  const int q4 = l >> 4;
  const int b  = blockIdx.y;
  const int m0 = blockIdx.x * 64;

  const bf16_t* qb = q + (size_t)b * NN * II;
  const bf16_t* kb = k + (size_t)b * NN * II;
  const bf16_t* vb = v + (size_t)b * CC * NN;

  // Q B-frags, loop-invariant, in registers
  bf16x8 qf[4];
#pragma unroll
  for (int mt = 0; mt < 4; ++mt)
    qf[mt] = *(const bf16x8*)(qb + (size_t)(m0 + mt * 16 + lo) * II + q4 * 8);

  f32x4 acc[4][4];  // [ct][mt]
#pragma unroll
  for (int ct = 0; ct < 4; ++ct)
#pragma unroll
    for (int mt = 0; mt < 4; ++mt) acc[ct][mt] = (f32x4){0.f, 0.f, 0.f, 0.f};
  float lp[4] = {0.f, 0.f, 0.f, 0.f};

  const int cbase = w * 64;
  const f32x4 zero = (f32x4){0.f, 0.f, 0.f, 0.f};

  // Prime K frag for n1 = 0
  bf16x8 kf = *(const bf16x8*)(kb + (size_t)(w * 16 + lo) * II + q4 * 8);

  for (int n1 = 0, it = 0; n1 < NN; n1 += 64, ++it) {
    // ---- issue V frags for THIS iter + K frag for NEXT iter up front ----
    bf16x8 vf[8];
#pragma unroll
    for (int kc = 0; kc < 2; ++kc)
#pragma unroll
      for (int ct = 0; ct < 4; ++ct)
        vf[kc * 4 + ct] = *(const bf16x8*)(vb +
            (size_t)(cbase + ct * 16 + lo) * NN + n1 + kc * 32 + q4 * 8);
    const int n_next = (n1 + 64) & (NN - 1);  // wraps to 0 on last iter (discarded)
    bf16x8 kf_next = *(const bf16x8*)(kb + (size_t)(n_next + w * 16 + lo) * II + q4 * 8);

    // ---- Phase 1: scores for n-sub w ----
    bf16_t* Pb = Pld[it & 1];
#pragma unroll
    for (int mt = 0; mt < 4; ++mt) {
      f32x4 s = __builtin_amdgcn_mfma_f32_16x16x32_bf16(kf, qf[mt], zero, 0, 0, 0);
      float e0 = __expf(s[0]), e1 = __expf(s[1]), e2 = __expf(s[2]), e3 = __expf(s[3]);
      lp[mt] += (e0 + e1) + (e2 + e3);
      union { bf16_t h[4]; uint2 u2; } ph;
      ph.h[0] = (bf16_t)e0; ph.h[1] = (bf16_t)e1;
      ph.h[2] = (bf16_t)e2; ph.h[3] = (bf16_t)e3;
      // P[m][n_local], n_local = w*16 + q4*4 + r. 16B chunk c8 at row m
      // lives at phys chunk c8 ^ (m&7). Write = 8B half-chunk.
      int m_loc = mt * 16 + lo;
      int c8    = w * 2 + (q4 >> 1);
      int elem  = m_loc * 64 + ((c8 ^ (m_loc & 7)) * 8) + (q4 & 1) * 4;
      *(uint2*)&Pb[elem] = ph.u2;
    }

    // ---- RELAXED barrier: order LDS P writes only; V/K loads stay in
    //      flight (old __syncthreads drained vmcnt(0) here = the stall) ----
    asm volatile("s_waitcnt lgkmcnt(0)" ::: "memory");
    __builtin_amdgcn_s_barrier();
    __builtin_amdgcn_sched_barrier(0);  // don't hoist ds_reads above barrier

    // ---- Phase 2: PV ----
#pragma unroll
    for (int kc = 0; kc < 2; ++kc) {
      bf16x8 pf[4];
#pragma unroll
      for (int mt = 0; mt < 4; ++mt) {
        int m_loc = mt * 16 + lo;
        int c8    = kc * 4 + q4;
        pf[mt] = *(const bf16x8*)&Pb[m_loc * 64 + ((c8 ^ (m_loc & 7)) * 8)];
      }
      __builtin_amdgcn_s_setprio(1);
#pragma unroll
      for (int ct = 0; ct < 4; ++ct)
#pragma unroll
        for (int mt = 0; mt < 4; ++mt)
          acc[ct][mt] = __builtin_amdgcn_mfma_f32_16x16x32_bf16(
              vf[kc * 4 + ct], pf[mt], acc[ct][mt], 0, 0, 0);
      __builtin_amdgcn_s_setprio(0);
    }
    kf = kf_next;
  }

  // ---- softmax denominator reduction ----
#pragma unroll
  for (int mt = 0; mt < 4; ++mt) lred[w * 4 + q4][mt * 16 + lo] = lp[mt];
  __syncthreads();
  if (t < 64) {
    float s = 0.f;
#pragma unroll
    for (int j = 0; j < 16; ++j) s += lred[j][t];
    lfin[t] = s;
  }
  __syncthreads();

  const float g = gamma[0];
  float linv[4];
#pragma unroll
  for (int mt = 0; mt < 4; ++mt) linv[mt] = 1.0f / lfin[mt * 16 + lo];

  // ---- epilogue: out = gamma * O/l + x ----
#pragma unroll
  for (int ct = 0; ct < 4; ++ct) {
#pragma unroll
    for (int r = 0; r < 4; ++r) {
      int c = cbase + ct * 16 + q4 * 4 + r;
      const float* xrow = x + ((size_t)b * CC + c) * NN + m0;
      float* orow       = out + ((size_t)b * CC + c) * NN + m0;
#pragma unroll
      for (int mt = 0; mt < 4; ++mt) {
        int m = mt * 16 + lo;
        orow[m] = g * acc[ct][mt][r] * linv[mt] + xrow[m];
      }
    }
  }
}

// ---------------------------------------------------------------------------
extern "C" void kernel_launch(void* const* d_in, const int* in_sizes, int n_in,
                              void* d_out, int out_size, void* d_ws, size_t ws_size,
                              hipStream_t stream) {
  const float* x     = (const float*)d_in[0];
  const float* Wq    = (const float*)d_in[1];
  const float* bq    = (const float*)d_in[2];
  const float* Wk    = (const float*)d_in[3];
  const float* bk    = (const float*)d_in[4];
  const float* Wv    = (const float*)d_in[5];
  const float* bv    = (const float*)d_in[6];
  const float* gamma = (const float*)d_in[7];
  float* out = (float*)d_out;

  // Workspace (bf16): q 2MB, k 2MB, v 16MB, Wb 160KB, xt 16MB (~36.2MB)
  bf16_t* ws = (bf16_t*)d_ws;
  bf16_t* q  = ws;
  bf16_t* k  = q + (size_t)BB * NN * II;
  bf16_t* v  = k + (size_t)BB * NN * II;
  bf16_t* Wb = v + (size_t)BB * CC * NN;
  bf16_t* xt = Wb + (size_t)320 * 256;

  wconv<<<dim3(320), 256, 0, stream>>>(Wq, Wk, Wv, Wb);

  dim3 gx(NN / 64, CC / 64, BB);
  xcvt<<<gx, 256, 0, stream>>>(x, xt);

  dim3 gp(NN / 128, 4, BB);
  qkv_proj<<<gp, 256, 0, stream>>>(xt, Wb, bq, bk, bv, q, k, v);

  dim3 ga(NN / 64, BB);
  attn_mfma<<<ga, 256, 0, stream>>>(q, k, v, x, gamma, out);
}